// Round 1
// baseline (112.773 us; speedup 1.0000x reference)
//
#include <hip/hip_runtime.h>

#define SS 384
#define BB 2
#define DD 256
#define NPART 1024

// ws float layout:
//  [0]            Wtot
//  [16..16+1024)  W partial sums
//  [2048..2816)   m1 row sums  (b*S+i)
//  [2816..3584)   m2 row sums
//  [3584..4352)   m3 row sums, scaled in-place by Wtot/16
#define WS_PART 16
#define WS_M1 2048
#define WS_M2 2816
#define WS_M3 3584

// --- row sums of the three [B,S,D] matrices: one wave per row (D=256 -> float4/lane)
__global__ void rowsum_kernel(const float* __restrict__ m1,
                              const float* __restrict__ m2,
                              const float* __restrict__ m3,
                              float* __restrict__ ws) {
    int wave = (blockIdx.x * blockDim.x + threadIdx.x) >> 6;
    int lane = threadIdx.x & 63;
    if (wave >= 3 * BB * SS) return;
    const float* src;
    float* dst;
    if (wave < BB * SS)          { src = m1 + (size_t)wave * DD;               dst = ws + WS_M1 + wave; }
    else if (wave < 2 * BB * SS) { src = m2 + (size_t)(wave - BB * SS) * DD;   dst = ws + WS_M2 + (wave - BB * SS); }
    else                         { src = m3 + (size_t)(wave - 2 * BB * SS) * DD; dst = ws + WS_M3 + (wave - 2 * BB * SS); }
    float4 v = ((const float4*)src)[lane];
    float s = (v.x + v.y) + (v.z + v.w);
    #pragma unroll
    for (int off = 32; off; off >>= 1) s += __shfl_down(s, off, 64);
    if (lane == 0) *dst = s;
}

// --- stage 1: deterministic per-block partial sums of W (16.7M floats)
__global__ void wsum_part_kernel(const float* __restrict__ W, float* __restrict__ ws) {
    __shared__ float sm[4];
    const float4* W4 = (const float4*)W;
    const unsigned n4 = (DD * DD * DD) / 4;  // 4194304
    float s = 0.f;
    for (unsigned i = blockIdx.x * blockDim.x + threadIdx.x; i < n4; i += gridDim.x * blockDim.x) {
        float4 v = W4[i];
        s += (v.x + v.y) + (v.z + v.w);
    }
    #pragma unroll
    for (int off = 32; off; off >>= 1) s += __shfl_down(s, off, 64);
    int lane = threadIdx.x & 63, w = threadIdx.x >> 6;
    if (lane == 0) sm[w] = s;
    __syncthreads();
    if (threadIdx.x == 0) ws[WS_PART + blockIdx.x] = (sm[0] + sm[1]) + (sm[2] + sm[3]);
}

// --- stage 2: reduce partials -> Wtot; fold Wtot/16 into the m3 row sums
__global__ void wsum_final_kernel(float* __restrict__ ws) {
    __shared__ float sm[4];
    __shared__ float smTot;
    float s = 0.f;
    for (int i = threadIdx.x; i < NPART; i += 256) s += ws[WS_PART + i];
    #pragma unroll
    for (int off = 32; off; off >>= 1) s += __shfl_down(s, off, 64);
    int lane = threadIdx.x & 63, w = threadIdx.x >> 6;
    if (lane == 0) sm[w] = s;
    __syncthreads();
    if (threadIdx.x == 0) {
        float t = (sm[0] + sm[1]) + (sm[2] + sm[3]);
        ws[0] = t;
        smTot = t;
    }
    __syncthreads();
    float c = smTot * (1.0f / 16.0f);   // SCALE = sqrt(768/3) = 16
    for (int i = threadIdx.x; i < BB * SS; i += 256) ws[WS_M3 + i] *= c;
}

// --- the heavy kernel: masked rank-1 outer-product write, float4 stores
__global__ void writer_kernel(const float* __restrict__ ws, float* __restrict__ out) {
    const float* m1s = ws + WS_M1;
    const float* m2s = ws + WS_M2;
    const float* f3  = ws + WS_M3;  // m3 row sums * Wtot/16
    const unsigned K4 = SS / 4;                          // 96 float4 per k-row
    const unsigned total4 = BB * SS * SS * K4;           // 28,311,552
    const unsigned stride = gridDim.x * blockDim.x;
    for (unsigned n = blockIdx.x * blockDim.x + threadIdx.x; n < total4; n += stride) {
        unsigned k4 = n % K4;
        unsigned t  = n / K4;
        unsigned j  = t % SS;
        unsigned t2 = t / SS;
        unsigned i  = t2 % SS;
        unsigned b  = t2 / SS;
        float c = m1s[b * SS + i] * m2s[b * SS + j];
        float4 f = ((const float4*)(f3 + b * SS))[k4];
        int k0 = (int)(k4 * 4);
        int jj = (int)j;
        float4 o;
        o.x = (k0 + 0 > jj) ? c * f.x : 0.f;
        o.y = (k0 + 1 > jj) ? c * f.y : 0.f;
        o.z = (k0 + 2 > jj) ? c * f.z : 0.f;
        o.w = (k0 + 3 > jj) ? c * f.w : 0.f;
        ((float4*)out)[n] = o;
    }
}

extern "C" void kernel_launch(void* const* d_in, const int* in_sizes, int n_in,
                              void* d_out, int out_size, void* d_ws, size_t ws_size,
                              hipStream_t stream) {
    const float* m1 = (const float*)d_in[0];
    const float* m2 = (const float*)d_in[1];
    const float* m3 = (const float*)d_in[2];
    const float* W  = (const float*)d_in[3];
    float* out = (float*)d_out;
    float* ws  = (float*)d_ws;

    // row sums: 3*2*384 = 2304 waves, 4 waves/block -> 576 blocks
    rowsum_kernel<<<576, 256, 0, stream>>>(m1, m2, m3, ws);
    // W reduction
    wsum_part_kernel<<<NPART, 256, 0, stream>>>(W, ws);
    wsum_final_kernel<<<1, 256, 0, stream>>>(ws);
    // masked outer-product write (453 MB)
    writer_kernel<<<2048, 256, 0, stream>>>(ws, out);
}

// Round 2
// 111.407 us; speedup vs baseline: 1.0123x; 1.0123x over previous
//
#include <hip/hip_runtime.h>

#define SS 384
#define BB 2
#define DD 256
#define NPART 1024

// ws float layout:
//  [0]            Wtot
//  [16..16+1024)  W partial sums
//  [2048..2816)   m1 row sums  (b*S+i)
//  [2816..3584)   m2 row sums
//  [3584..4352)   m3 row sums, scaled in-place by Wtot/16
#define WS_PART 16
#define WS_M1 2048
#define WS_M2 2816
#define WS_M3 3584

// --- fused stage 1: blocks [0,NPART) do W partial sums; blocks [NPART, NPART+576) do row sums
__global__ void stage1_kernel(const float* __restrict__ m1,
                              const float* __restrict__ m2,
                              const float* __restrict__ m3,
                              const float* __restrict__ W,
                              float* __restrict__ ws) {
    if (blockIdx.x < NPART) {
        // deterministic per-block partial sums of W (16.7M floats)
        __shared__ float sm[4];
        const float4* W4 = (const float4*)W;
        const unsigned n4 = (DD * DD * DD) / 4;  // 4194304
        float s = 0.f;
        for (unsigned i = blockIdx.x * blockDim.x + threadIdx.x; i < n4; i += NPART * 256) {
            float4 v = W4[i];
            s += (v.x + v.y) + (v.z + v.w);
        }
        #pragma unroll
        for (int off = 32; off; off >>= 1) s += __shfl_down(s, off, 64);
        int lane = threadIdx.x & 63, w = threadIdx.x >> 6;
        if (lane == 0) sm[w] = s;
        __syncthreads();
        if (threadIdx.x == 0) ws[WS_PART + blockIdx.x] = (sm[0] + sm[1]) + (sm[2] + sm[3]);
    } else {
        // row sums: one wave per row, D=256 -> float4/lane
        int wave = (int)(blockIdx.x - NPART) * 4 + (int)(threadIdx.x >> 6);
        int lane = threadIdx.x & 63;
        if (wave >= 3 * BB * SS) return;
        const float* src;
        float* dst;
        if (wave < BB * SS)          { src = m1 + (size_t)wave * DD;                 dst = ws + WS_M1 + wave; }
        else if (wave < 2 * BB * SS) { src = m2 + (size_t)(wave - BB * SS) * DD;     dst = ws + WS_M2 + (wave - BB * SS); }
        else                         { src = m3 + (size_t)(wave - 2 * BB * SS) * DD; dst = ws + WS_M3 + (wave - 2 * BB * SS); }
        float4 v = ((const float4*)src)[lane];
        float s = (v.x + v.y) + (v.z + v.w);
        #pragma unroll
        for (int off = 32; off; off >>= 1) s += __shfl_down(s, off, 64);
        if (lane == 0) *dst = s;
    }
}

// --- stage 2: reduce partials -> Wtot; fold Wtot/16 into the m3 row sums
__global__ void wsum_final_kernel(float* __restrict__ ws) {
    __shared__ float sm[4];
    __shared__ float smTot;
    float s = 0.f;
    for (int i = threadIdx.x; i < NPART; i += 256) s += ws[WS_PART + i];
    #pragma unroll
    for (int off = 32; off; off >>= 1) s += __shfl_down(s, off, 64);
    int lane = threadIdx.x & 63, w = threadIdx.x >> 6;
    if (lane == 0) sm[w] = s;
    __syncthreads();
    if (threadIdx.x == 0) {
        float t = (sm[0] + sm[1]) + (sm[2] + sm[3]);
        ws[0] = t;
        smTot = t;
    }
    __syncthreads();
    float c = smTot * (1.0f / 16.0f);   // SCALE = sqrt(768/3) = 16
    for (int i = threadIdx.x; i < BB * SS; i += 256) ws[WS_M3 + i] *= c;
}

// --- heavy kernel: one block per (b,i) slab [S_j, S_k]; 384 threads.
// thread t: k4 = t%96 (fixed float4 column), jrow = t/96; loops j += 4.
// Per-iteration body: 1 broadcast load + cmp/sel/mul + 1 coalesced float4 store.
__global__ void __launch_bounds__(384) writer_kernel(const float* __restrict__ ws,
                                                     float* __restrict__ out) {
    int bi = blockIdx.x;                 // b*S + i
    int b  = bi / SS;
    const float* m2s = ws + WS_M2 + b * SS;
    const float* f3  = ws + WS_M3 + b * SS;   // m3 row sums * Wtot/16
    float c1 = ws[WS_M1 + bi];
    int t    = threadIdx.x;
    int jrow = t / 96;                   // 0..3
    int k4   = t - jrow * 96;            // 0..95
    float4 f = ((const float4*)f3)[k4];  // loaded ONCE
    int k0 = k4 * 4;
    float4* dst = (float4*)out + (size_t)bi * (SS * SS / 4);
    #pragma unroll 2
    for (int j = jrow; j < SS; j += 4) {
        float cj = c1 * m2s[j];
        float4 o;
        o.x = (k0 + 0 > j) ? cj * f.x : 0.f;
        o.y = (k0 + 1 > j) ? cj * f.y : 0.f;
        o.z = (k0 + 2 > j) ? cj * f.z : 0.f;
        o.w = (k0 + 3 > j) ? cj * f.w : 0.f;
        dst[j * 96 + k4] = o;
    }
}

extern "C" void kernel_launch(void* const* d_in, const int* in_sizes, int n_in,
                              void* d_out, int out_size, void* d_ws, size_t ws_size,
                              hipStream_t stream) {
    const float* m1 = (const float*)d_in[0];
    const float* m2 = (const float*)d_in[1];
    const float* m3 = (const float*)d_in[2];
    const float* W  = (const float*)d_in[3];
    float* out = (float*)d_out;
    float* ws  = (float*)d_ws;

    // fused: W partial sums (1024 blocks) + all row sums (576 blocks)
    stage1_kernel<<<NPART + 576, 256, 0, stream>>>(m1, m2, m3, W, ws);
    wsum_final_kernel<<<1, 256, 0, stream>>>(ws);
    // masked outer-product write (453 MB), one block per (b,i)
    writer_kernel<<<BB * SS, 384, 0, stream>>>(ws, out);
}

// Round 4
// 107.098 us; speedup vs baseline: 1.0530x; 1.0402x over previous
//
#include <hip/hip_runtime.h>

#define SS 384
#define BB 2
#define DD 256
#define NPART 1024

typedef float f32x4 __attribute__((ext_vector_type(4)));

// ws float layout:
//  [16..16+1024)  W partial sums
//  [2048..2816)   m1 row sums  (b*S+i)
//  [2816..3584)   m2 row sums
//  [3584..4352)   m3 row sums (raw)
#define WS_PART 16
#define WS_M1 2048
#define WS_M2 2816
#define WS_M3 3584

// --- fused stage 1: blocks [0,NPART) do W partial sums; blocks [NPART, NPART+576) do row sums
__global__ void stage1_kernel(const float* __restrict__ m1,
                              const float* __restrict__ m2,
                              const float* __restrict__ m3,
                              const float* __restrict__ W,
                              float* __restrict__ ws) {
    if (blockIdx.x < NPART) {
        // deterministic per-block partial sums of W (16.7M floats), NT loads (no reuse)
        __shared__ float sm[4];
        const f32x4* W4 = (const f32x4*)W;
        const unsigned n4 = (DD * DD * DD) / 4;  // 4194304
        float s = 0.f;
        for (unsigned i = blockIdx.x * blockDim.x + threadIdx.x; i < n4; i += NPART * 256) {
            f32x4 v = __builtin_nontemporal_load(&W4[i]);
            s += (v.x + v.y) + (v.z + v.w);
        }
        #pragma unroll
        for (int off = 32; off; off >>= 1) s += __shfl_down(s, off, 64);
        int lane = threadIdx.x & 63, w = threadIdx.x >> 6;
        if (lane == 0) sm[w] = s;
        __syncthreads();
        if (threadIdx.x == 0) ws[WS_PART + blockIdx.x] = (sm[0] + sm[1]) + (sm[2] + sm[3]);
    } else {
        // row sums: one wave per row, D=256 -> float4/lane
        int wave = (int)(blockIdx.x - NPART) * 4 + (int)(threadIdx.x >> 6);
        int lane = threadIdx.x & 63;
        if (wave >= 3 * BB * SS) return;
        const float* src;
        float* dst;
        if (wave < BB * SS)          { src = m1 + (size_t)wave * DD;                 dst = ws + WS_M1 + wave; }
        else if (wave < 2 * BB * SS) { src = m2 + (size_t)(wave - BB * SS) * DD;     dst = ws + WS_M2 + (wave - BB * SS); }
        else                         { src = m3 + (size_t)(wave - 2 * BB * SS) * DD; dst = ws + WS_M3 + (wave - 2 * BB * SS); }
        f32x4 v = ((const f32x4*)src)[lane];
        float s = (v.x + v.y) + (v.z + v.w);
        #pragma unroll
        for (int off = 32; off; off >>= 1) s += __shfl_down(s, off, 64);
        if (lane == 0) *dst = s;
    }
}

// --- heavy kernel: one block per (b,i) slab [S_j, S_k]; 384 threads.
// Prologue: every block redundantly reduces the 1024 W-partials (deterministic
// fixed-order sum, ~4KB from L2) -> Wtot/16 folded into the scalar c1.
// Main loop: 1 broadcast load + cmp/sel/mul + 1 NONTEMPORAL float4 store.
__global__ void __launch_bounds__(384) writer_kernel(const float* __restrict__ ws,
                                                     float* __restrict__ out) {
    __shared__ float sred[8];
    int t = threadIdx.x;
    // block-wide reduce of ws[WS_PART .. WS_PART+1024)
    {
        const float* p = ws + WS_PART;
        float s = p[t] + p[t + 384] + (t < 256 ? p[t + 768] : 0.f);
        #pragma unroll
        for (int off = 32; off; off >>= 1) s += __shfl_down(s, off, 64);
        int lane = t & 63, w = t >> 6;
        if (lane == 0) sred[w] = s;
        __syncthreads();
        if (t == 0) {
            float tot = ((sred[0] + sred[1]) + (sred[2] + sred[3])) + (sred[4] + sred[5]);
            sred[6] = tot * (1.0f / 16.0f);   // SCALE = sqrt(768/3) = 16
        }
        __syncthreads();
    }
    float wt16 = sred[6];

    int bi = blockIdx.x;                 // b*S + i
    int b  = bi / SS;
    const float* m2s = ws + WS_M2 + b * SS;
    const float* f3  = ws + WS_M3 + b * SS;   // raw m3 row sums
    float c1 = ws[WS_M1 + bi] * wt16;
    int jrow = t / 96;                   // 0..3
    int k4   = t - jrow * 96;            // 0..95
    f32x4 f = ((const f32x4*)f3)[k4];    // loaded ONCE
    int k0 = k4 * 4;
    f32x4* dst = (f32x4*)out + (size_t)bi * (SS * SS / 4);
    #pragma unroll 4
    for (int j = jrow; j < SS; j += 4) {
        float cj = c1 * m2s[j];
        f32x4 o;
        o.x = (k0 + 0 > j) ? cj * f.x : 0.f;
        o.y = (k0 + 1 > j) ? cj * f.y : 0.f;
        o.z = (k0 + 2 > j) ? cj * f.z : 0.f;
        o.w = (k0 + 3 > j) ? cj * f.w : 0.f;
        __builtin_nontemporal_store(o, &dst[j * 96 + k4]);
    }
}

extern "C" void kernel_launch(void* const* d_in, const int* in_sizes, int n_in,
                              void* d_out, int out_size, void* d_ws, size_t ws_size,
                              hipStream_t stream) {
    const float* m1 = (const float*)d_in[0];
    const float* m2 = (const float*)d_in[1];
    const float* m3 = (const float*)d_in[2];
    const float* W  = (const float*)d_in[3];
    float* out = (float*)d_out;
    float* ws  = (float*)d_ws;

    // fused: W partial sums (1024 blocks) + all row sums (576 blocks)
    stage1_kernel<<<NPART + 576, 256, 0, stream>>>(m1, m2, m3, W, ws);
    // masked outer-product write (453 MB), one block per (b,i); NT stores
    writer_kernel<<<BB * SS, 384, 0, stream>>>(ws, out);
}

// Round 5
// 105.861 us; speedup vs baseline: 1.0653x; 1.0117x over previous
//
#include <hip/hip_runtime.h>

#define SS 384
#define BB 2
#define DD 256
#define NPART 1024

typedef float f32x4 __attribute__((ext_vector_type(4)));

// ws float layout:
//  [16..16+1024)  W partial sums
//  [2048..2816)   m1 row sums  (b*S+i)
//  [2816..3584)   m2 row sums
//  [3584..4352)   m3 row sums (raw)
#define WS_PART 16
#define WS_M1 2048
#define WS_M2 2816
#define WS_M3 3584

// --- fused stage 1: blocks [0,NPART) do W partial sums; blocks [NPART, NPART+576) do row sums
__global__ void stage1_kernel(const float* __restrict__ m1,
                              const float* __restrict__ m2,
                              const float* __restrict__ m3,
                              const float* __restrict__ W,
                              float* __restrict__ ws) {
    if (blockIdx.x < NPART) {
        __shared__ float sm[4];
        const f32x4* W4 = (const f32x4*)W;
        const unsigned n4 = (DD * DD * DD) / 4;  // 4194304
        float s = 0.f;
        for (unsigned i = blockIdx.x * blockDim.x + threadIdx.x; i < n4; i += NPART * 256) {
            f32x4 v = __builtin_nontemporal_load(&W4[i]);
            s += (v.x + v.y) + (v.z + v.w);
        }
        #pragma unroll
        for (int off = 32; off; off >>= 1) s += __shfl_down(s, off, 64);
        int lane = threadIdx.x & 63, w = threadIdx.x >> 6;
        if (lane == 0) sm[w] = s;
        __syncthreads();
        if (threadIdx.x == 0) ws[WS_PART + blockIdx.x] = (sm[0] + sm[1]) + (sm[2] + sm[3]);
    } else {
        // row sums: one wave per row, D=256 -> float4/lane
        int wave = (int)(blockIdx.x - NPART) * 4 + (int)(threadIdx.x >> 6);
        int lane = threadIdx.x & 63;
        if (wave >= 3 * BB * SS) return;
        const float* src;
        float* dst;
        if (wave < BB * SS)          { src = m1 + (size_t)wave * DD;                 dst = ws + WS_M1 + wave; }
        else if (wave < 2 * BB * SS) { src = m2 + (size_t)(wave - BB * SS) * DD;     dst = ws + WS_M2 + (wave - BB * SS); }
        else                         { src = m3 + (size_t)(wave - 2 * BB * SS) * DD; dst = ws + WS_M3 + (wave - 2 * BB * SS); }
        f32x4 v = ((const f32x4*)src)[lane];
        float s = (v.x + v.y) + (v.z + v.w);
        #pragma unroll
        for (int off = 32; off; off >>= 1) s += __shfl_down(s, off, 64);
        if (lane == 0) *dst = s;
    }
}

// --- heavy kernel: one block per (b,i) slab [S_j, S_k]; 384 threads.
// CRITICAL PROPERTY: the store loop contains ZERO vmem loads (m2 row sums are
// staged in LDS; f3/c1 in registers). vmcnt counts loads AND stores in-order,
// so any vmem load in the loop would force draining all older stores —
// the suspected 5.0-vs-6.9 TB/s gap vs fillBuffer.
__global__ void __launch_bounds__(384) writer_kernel(const float* __restrict__ ws,
                                                     float* __restrict__ out) {
    __shared__ float sred[8];
    __shared__ float m2l[SS];
    int t  = threadIdx.x;
    int bi = blockIdx.x;                 // b*S + i
    int b  = bi >= SS ? 1 : 0;

    // --- prologue: all vmem loads happen HERE, before the store loop ---
    m2l[t] = ws[WS_M2 + b * SS + t];               // stage m2 row sums to LDS
    float r1 = ws[WS_M1 + bi];                     // m1 row sum (reg)
    int jrow = t / 96;                             // 0..3
    int k4   = t - jrow * 96;                      // 0..95
    f32x4 f = ((const f32x4*)(ws + WS_M3 + b * SS))[k4];  // m3 row sums (regs)

    // block-wide reduce of the 1024 W-partials (deterministic fixed order)
    const float* p = ws + WS_PART;
    float s = p[t] + p[t + 384] + (t < 256 ? p[t + 768] : 0.f);
    #pragma unroll
    for (int off = 32; off; off >>= 1) s += __shfl_down(s, off, 64);
    int lane = t & 63, w = t >> 6;
    if (lane == 0) sred[w] = s;
    __syncthreads();
    if (t == 0) {
        float tot = ((sred[0] + sred[1]) + (sred[2] + sred[3])) + (sred[4] + sred[5]);
        sred[6] = tot * (1.0f / 16.0f);  // SCALE = sqrt(768/3) = 16
    }
    __syncthreads();
    float c1 = r1 * sred[6];

    // --- store loop: ds_read + VALU + NT store only ---
    int k0 = k4 * 4;
    f32x4* dst = (f32x4*)out + (size_t)bi * (SS * SS / 4);
    #pragma unroll 4
    for (int j = jrow; j < SS; j += 4) {
        float cj = c1 * m2l[j];
        f32x4 o;
        o.x = (k0 + 0 > j) ? cj * f.x : 0.f;
        o.y = (k0 + 1 > j) ? cj * f.y : 0.f;
        o.z = (k0 + 2 > j) ? cj * f.z : 0.f;
        o.w = (k0 + 3 > j) ? cj * f.w : 0.f;
        __builtin_nontemporal_store(o, &dst[j * 96 + k4]);
    }
}

extern "C" void kernel_launch(void* const* d_in, const int* in_sizes, int n_in,
                              void* d_out, int out_size, void* d_ws, size_t ws_size,
                              hipStream_t stream) {
    const float* m1 = (const float*)d_in[0];
    const float* m2 = (const float*)d_in[1];
    const float* m3 = (const float*)d_in[2];
    const float* W  = (const float*)d_in[3];
    float* out = (float*)d_out;
    float* ws  = (float*)d_ws;

    // fused: W partial sums (1024 blocks) + all row sums (576 blocks)
    stage1_kernel<<<NPART + 576, 256, 0, stream>>>(m1, m2, m3, W, ws);
    // masked outer-product write (453 MB), one block per (b,i); load-free store loop
    writer_kernel<<<BB * SS, 384, 0, stream>>>(ws, out);
}